// Round 5
// baseline (219.377 us; speedup 1.0000x reference)
//
#include <hip/hip_runtime.h>
#include <hip/hip_bf16.h>

#define T_TOK 2048
#define DM 1024
#define DH 2048
#define NE 8
#define MT_MAX 40   // max live (expert, m-tile) pairs: 4096/128 + 8

using bf16x8 = __attribute__((ext_vector_type(8))) short;
using f32x4  = __attribute__((ext_vector_type(4))) float;

__device__ __forceinline__ unsigned short f2bf(float f) {
  union { float f; unsigned u; } v; v.f = f;
  unsigned r = v.u + 0x7FFFu + ((v.u >> 16) & 1u);
  return (unsigned short)(r >> 16);
}
__device__ __forceinline__ unsigned pk2(float a, float b) {
  return (unsigned)f2bf(a) | ((unsigned)f2bf(b) << 16);
}

// async global->LDS, 16B per lane; dest wave-uniform base (lane*16 implicit)
#define GLOAD16(gsrc, ldst)                                                        \
  __builtin_amdgcn_global_load_lds(                                                \
      (const __attribute__((address_space(1))) unsigned int*)(gsrc),               \
      (__attribute__((address_space(3))) unsigned int*)(ldst), 16, 0, 0)

// ---------------- init: zero per-expert counters ----------------
__global__ void k_init(int* __restrict__ cnt) {
  if (threadIdx.x < NE) cnt[threadIdx.x] = 0;
}

// ==== fused launch: router (blocks 0..511) + weight transpose-convert =======
// conv: f32 [E][R][C] -> bf16 [E][C][R]. Register 4x4 transpose, bank-floor
// LDS (slot-swizzle (k>>3)^((n>>2)&7)), double-buffered, 4 tiles/block.
__global__ __launch_bounds__(256) void k_wconv(
    const float* __restrict__ x, const float* __restrict__ Wr, const float* __restrict__ br,
    int* __restrict__ cnt, int* __restrict__ idx, float* __restrict__ wgt,
    int* __restrict__ t2r, float* __restrict__ probs, unsigned short* __restrict__ xb,
    const float* __restrict__ W1, const float* __restrict__ W2, const float* __restrict__ Wo,
    unsigned short* __restrict__ W1T, unsigned short* __restrict__ W2T,
    unsigned short* __restrict__ WoT)
{
  __shared__ __align__(16) unsigned short tb[2][64*64];  // 2 x 8 KB
  const int tid = threadIdx.x;

  if (blockIdx.x < 512) {
    // ---------------- router path: 4 tokens per block, 1 wave each ----------
    const int wave = tid >> 6, l = tid & 63;
    const int tok = blockIdx.x * 4 + wave;
    float xv[16];
#pragma unroll
    for (int i = 0; i < 16; ++i) xv[i] = x[tok*DM + l + 64*i];
#pragma unroll
    for (int i = 0; i < 16; ++i) xb[tok*DM + l + 64*i] = f2bf(xv[i]);

    float acc[8] = {0.f,0.f,0.f,0.f,0.f,0.f,0.f,0.f};
#pragma unroll
    for (int i = 0; i < 16; ++i) {
      const float4* wp = (const float4*)&Wr[(size_t)(l + 64*i)*NE];
      float4 wa = wp[0], wb = wp[1];
      acc[0] += xv[i]*wa.x; acc[1] += xv[i]*wa.y; acc[2] += xv[i]*wa.z; acc[3] += xv[i]*wa.w;
      acc[4] += xv[i]*wb.x; acc[5] += xv[i]*wb.y; acc[6] += xv[i]*wb.z; acc[7] += xv[i]*wb.w;
    }
#pragma unroll
    for (int e = 0; e < 8; ++e) {
#pragma unroll
      for (int off = 32; off; off >>= 1) acc[e] += __shfl_xor(acc[e], off, 64);
      acc[e] += br[e];
    }
    float mx = acc[0];
#pragma unroll
    for (int e = 1; e < 8; ++e) mx = fmaxf(mx, acc[e]);
    float p[8], s = 0.f;
#pragma unroll
    for (int e = 0; e < 8; ++e) { p[e] = expf(acc[e] - mx); s += p[e]; }
    float inv = 1.f / s;
#pragma unroll
    for (int e = 0; e < 8; ++e) p[e] *= inv;

    // top-2, strict > so lowest index wins ties (matches jax.lax.top_k)
    int e0 = 0; float p0 = p[0];
#pragma unroll
    for (int e = 1; e < 8; ++e) if (p[e] > p0) { p0 = p[e]; e0 = e; }
    int e1 = -1; float p1 = -1.f;
#pragma unroll
    for (int e = 0; e < 8; ++e) { if (e == e0) continue; if (p[e] > p1) { p1 = p[e]; e1 = e; } }

    if (l == 0) {
#pragma unroll
      for (int e = 0; e < 8; ++e) probs[tok*NE + e] = p[e];
      int pos0 = atomicAdd(&cnt[e0], 1);
      idx[e0*T_TOK + pos0] = tok; wgt[e0*T_TOK + pos0] = p0;
      t2r[tok*2 + 0] = e0*T_TOK + pos0;
      int pos1 = atomicAdd(&cnt[e1], 1);
      idx[e1*T_TOK + pos1] = tok; wgt[e1*T_TOK + pos1] = p1;
      t2r[tok*2 + 1] = e1*T_TOK + pos1;
    }
    return;
  }

  // ---------------- conv path ------------------------------------------------
  const int bx = tid >> 4;   // k-quad 0..15 (k0 = bx*4)
  const int by = tid & 15;   // n-quad 0..15 (n0 = by*4)
  const int rn = tid >> 3;   // drain: n-row 0..31 (+32)
  const int sl8 = tid & 7;   // drain: k-slot 0..7

#pragma unroll
  for (int it = 0; it < 4; ++it) {
    int tt = (blockIdx.x - 512) * 4 + it;   // 0..12287
    const float* in; unsigned short* outT; int nCs;
    int R, C;
    if (tt < 4096)      { in = W1; outT = W1T; R = DM; C = DH; nCs = 5; }
    else if (tt < 8192) { in = W2; outT = W2T; R = DM; C = DH; nCs = 5; tt -= 4096; }
    else                { in = Wo; outT = WoT; R = DH; C = DM; nCs = 4; tt -= 8192; }
    const int e  = tt >> 9;          // 512 tiles/expert in every case
    const int te = tt & 511;
    const int r0 = (te >> nCs) << 6;
    const int c0 = (te & ((1 << nCs) - 1)) << 6;

    // read 4x4 f32 micro-block: rows r0+bx*4+i, cols c0+by*4 (+0..3)
    float4 v[4];
#pragma unroll
    for (int i = 0; i < 4; ++i)
      v[i] = *(const float4*)&in[((size_t)e*R + r0 + bx*4 + i)*C + c0 + by*4];

    // register transpose+convert -> swizzled LDS, 4x ds_write_b64 (bank floor)
    unsigned short* B = tb[it & 1];
#pragma unroll
    for (int j = 0; j < 4; ++j) {
      int n = by*4 + j;
      uint2 w;
      w.x = pk2(((const float*)&v[0])[j], ((const float*)&v[1])[j]);
      w.y = pk2(((const float*)&v[2])[j], ((const float*)&v[3])[j]);
      int byteoff = n*128 + (((bx >> 1) ^ ((n >> 2) & 7)) * 16) + (bx & 1) * 8;
      *(uint2*)((char*)B + byteoff) = w;
    }
    __syncthreads();

    // drain: b128 swizzled reads -> 128B-coalesced global stores
#pragma unroll
    for (int h = 0; h < 2; ++h) {
      int n = rn + h*32;
      int byteoff = n*128 + ((sl8 ^ ((n >> 2) & 7)) * 16);
      uint4 w = *(const uint4*)((const char*)B + byteoff);
      *(uint4*)&outT[((size_t)e*C + c0 + n)*R + r0 + sl8*8] = w;
    }
    // next iter writes the other buffer; reads of this buffer complete before
    // the next sync, which precedes any overwrite of it (2-deep rotation).
  }
}

// ------ finalize: row_base prefix + lb_loss + compact work table ------------
__global__ __launch_bounds__(256) void k_finalize(
    const int* __restrict__ cnt, int* __restrict__ rb,
    const float* __restrict__ probs, float* __restrict__ out,
    int* __restrict__ MTp, int* __restrict__ mtab)
{
  __shared__ float red[8][256];
  const int tid = threadIdx.x;
  float s[8] = {0.f,0.f,0.f,0.f,0.f,0.f,0.f,0.f};
  for (int t = tid; t < T_TOK; t += 256) {
#pragma unroll
    for (int e = 0; e < 8; ++e) s[e] += probs[t*NE + e];
  }
#pragma unroll
  for (int e = 0; e < 8; ++e) red[e][tid] = s[e];
  __syncthreads();
  for (int w = 128; w > 0; w >>= 1) {
    if (tid < w) {
#pragma unroll
      for (int e = 0; e < 8; ++e) red[e][tid] += red[e][tid + w];
    }
    __syncthreads();
  }
  if (tid == 0) {
    float lb = 0.f;
#pragma unroll
    for (int e = 0; e < 8; ++e) {
      float mean = red[e][0] * (1.f / T_TOK);
      lb += mean * mean;
    }
    out[2097152] = lb * NE;
    int r = 0, mc = 0;
#pragma unroll
    for (int e = 0; e < 8; ++e) {
      rb[e] = r; r += cnt[e];
      int nmt = (cnt[e] + 127) / 128;
      for (int j = 0; j < nmt; ++j) mtab[mc++] = (e << 16) | j;
    }
    *MTp = mc;
  }
}

#define TM1 128
#define TN1 64
#define BKK 64

// ---- FFN1: h,g GEMMs + SwiGLU -> act (bf16). Compact grid, 1-buf 2-barrier. -
__global__ __launch_bounds__(256) void k_ffn1b(
    const unsigned short* __restrict__ xb,
    const unsigned short* __restrict__ W1T, const float* __restrict__ b1,
    const unsigned short* __restrict__ W2T, const float* __restrict__ b2,
    const int* __restrict__ cnt, const int* __restrict__ rbp,
    const int* __restrict__ idx, unsigned short* __restrict__ act,
    const int* __restrict__ MTp, const int* __restrict__ mtab)
{
  const int mtg = blockIdx.y;
  if (mtg >= *MTp) return;
  const int code = mtab[mtg];
  const int e = code >> 16, mt = code & 0xffff;
  const int Me = cnt[e];
  const int m0 = mt * TM1;
  const int nt = blockIdx.x;
  const int n0 = nt * TN1;

  __shared__ __align__(16) unsigned short As[TM1*BKK];  // 16 KB
  __shared__ __align__(16) unsigned short Bh[TN1*BKK];  // 8 KB
  __shared__ __align__(16) unsigned short Bg[TN1*BKK];  // 8 KB
  __shared__ int toks[TM1];

  const int tid = threadIdx.x;
  if (tid < TM1) toks[tid] = idx[e*T_TOK + min(m0 + tid, Me - 1)];
  __syncthreads();

  const int lane = tid & 63;
  const int wave = tid >> 6;
  const int wm = wave >> 1, wn = wave & 1;
  const int row16 = lane & 15, kg = lane >> 4;
  const int sl = lane & 7;   // 16B slot within 128B row
  const int lr = lane >> 3;  // row within 8-row wave chunk

  // hoisted stage-source pointers (swizzle folded into the base)
  const unsigned short* asrc[4];
#pragma unroll
  for (int i = 0; i < 4; ++i) {
    int r = (wave*4 + i)*8 + lr;
    asrc[i] = &xb[(size_t)toks[r]*DM + ((sl ^ (r & 7)) * 8)];
  }
  const unsigned short *bsrc1[2], *bsrc2[2];
#pragma unroll
  for (int j = 0; j < 2; ++j) {
    int r = (wave*2 + j)*8 + lr;
    size_t gb = ((size_t)e*DH + n0 + r)*DM + ((sl ^ (r & 7)) * 8);
    bsrc1[j] = &W1T[gb]; bsrc2[j] = &W2T[gb];
  }

  f32x4 ah[4][2], ag[4][2];
#pragma unroll
  for (int i = 0; i < 4; ++i)
#pragma unroll
    for (int j = 0; j < 2; ++j) { ah[i][j] = 0.f; ag[i][j] = 0.f; }

  for (int k0 = 0; k0 < DM; k0 += BKK) {
#pragma unroll
    for (int i = 0; i < 4; ++i)
      GLOAD16(asrc[i] + k0, &As[(wave*4 + i)*512]);
#pragma unroll
    for (int j = 0; j < 2; ++j) {
      GLOAD16(bsrc1[j] + k0, &Bh[(wave*2 + j)*512]);
      GLOAD16(bsrc2[j] + k0, &Bg[(wave*2 + j)*512]);
    }
    __syncthreads();
#pragma unroll
    for (int ks = 0; ks < 2; ++ks) {
      const int kslot = ks*4 + kg;
      bf16x8 a[4], vbh[2], vbg[2];
#pragma unroll
      for (int mi = 0; mi < 4; ++mi) {
        int m = wm*64 + mi*16 + row16;
        a[mi] = *(const bf16x8*)&As[m*BKK + ((kslot ^ (m & 7)) * 8)];
      }
#pragma unroll
      for (int ni = 0; ni < 2; ++ni) {
        int n = wn*32 + ni*16 + row16;
        int off = n*BKK + ((kslot ^ (n & 7)) * 8);
        vbh[ni] = *(const bf16x8*)&Bh[off];
        vbg[ni] = *(const bf16x8*)&Bg[off];
      }
#pragma unroll
      for (int mi = 0; mi < 4; ++mi)
#pragma unroll
        for (int ni = 0; ni < 2; ++ni) {
          ah[mi][ni] = __builtin_amdgcn_mfma_f32_16x16x32_bf16(a[mi], vbh[ni], ah[mi][ni], 0, 0, 0);
          ag[mi][ni] = __builtin_amdgcn_mfma_f32_16x16x32_bf16(a[mi], vbg[ni], ag[mi][ni], 0, 0, 0);
        }
    }
    __syncthreads();
  }

  const int rb = rbp[e];
#pragma unroll
  for (int mi = 0; mi < 4; ++mi) {
#pragma unroll
    for (int i = 0; i < 4; ++i) {
      int rloc = wm*64 + mi*16 + (lane >> 4)*4 + i;
      int m = m0 + rloc;
      if (m < Me) {
#pragma unroll
        for (int ni = 0; ni < 2; ++ni) {
          int col = n0 + wn*32 + ni*16 + row16;
          float h = ah[mi][ni][i] + b1[e*DH + col];
          float g = ag[mi][ni][i] + b2[e*DH + col];
          float sg = g / (1.f + __expf(-g));
          act[(size_t)(rb + m)*DH + col] = f2bf(h * sg);
        }
      }
    }
  }
}

// ---- FFN2: act @ WoT -> ys (f32). Compact grid, 1-buf 2-barrier. -----------
__global__ __launch_bounds__(256) void k_ffn2b(
    const unsigned short* __restrict__ act,
    const unsigned short* __restrict__ WoT, const float* __restrict__ bo,
    const int* __restrict__ cnt, const int* __restrict__ rbp,
    float* __restrict__ ys,
    const int* __restrict__ MTp, const int* __restrict__ mtab)
{
  const int mtg = blockIdx.y;
  if (mtg >= *MTp) return;
  const int code = mtab[mtg];
  const int e = code >> 16, mt = code & 0xffff;
  const int Me = cnt[e];
  const int m0 = mt * TM1;
  const int nt = blockIdx.x;
  const int n0 = nt * TN1;
  const int rb = rbp[e];

  __shared__ __align__(16) unsigned short As[TM1*BKK];  // 16 KB
  __shared__ __align__(16) unsigned short Bs[TN1*BKK];  // 8 KB

  const int tid = threadIdx.x;
  const int lane = tid & 63;
  const int wave = tid >> 6;
  const int wm = wave >> 1, wn = wave & 1;
  const int row16 = lane & 15, kg = lane >> 4;
  const int sl = lane & 7;
  const int lr = lane >> 3;

  const unsigned short* asrc[4];
#pragma unroll
  for (int i = 0; i < 4; ++i) {
    int r = (wave*4 + i)*8 + lr;
    int grow = rb + min(m0 + r, Me - 1);
    asrc[i] = &act[(size_t)grow*DH + ((sl ^ (r & 7)) * 8)];
  }
  const unsigned short* bsrc[2];
#pragma unroll
  for (int j = 0; j < 2; ++j) {
    int r = (wave*2 + j)*8 + lr;
    bsrc[j] = &WoT[((size_t)e*DM + n0 + r)*DH + ((sl ^ (r & 7)) * 8)];
  }

  f32x4 acc[4][2];
#pragma unroll
  for (int i = 0; i < 4; ++i)
#pragma unroll
    for (int j = 0; j < 2; ++j) acc[i][j] = 0.f;

  for (int k0 = 0; k0 < DH; k0 += BKK) {
#pragma unroll
    for (int i = 0; i < 4; ++i)
      GLOAD16(asrc[i] + k0, &As[(wave*4 + i)*512]);
#pragma unroll
    for (int j = 0; j < 2; ++j)
      GLOAD16(bsrc[j] + k0, &Bs[(wave*2 + j)*512]);
    __syncthreads();
#pragma unroll
    for (int ks = 0; ks < 2; ++ks) {
      const int kslot = ks*4 + kg;
      bf16x8 a[4], b[2];
#pragma unroll
      for (int mi = 0; mi < 4; ++mi) {
        int m = wm*64 + mi*16 + row16;
        a[mi] = *(const bf16x8*)&As[m*BKK + ((kslot ^ (m & 7)) * 8)];
      }
#pragma unroll
      for (int ni = 0; ni < 2; ++ni) {
        int n = wn*32 + ni*16 + row16;
        b[ni] = *(const bf16x8*)&Bs[n*BKK + ((kslot ^ (n & 7)) * 8)];
      }
#pragma unroll
      for (int mi = 0; mi < 4; ++mi)
#pragma unroll
        for (int ni = 0; ni < 2; ++ni)
          acc[mi][ni] = __builtin_amdgcn_mfma_f32_16x16x32_bf16(a[mi], b[ni], acc[mi][ni], 0, 0, 0);
    }
    __syncthreads();
  }

#pragma unroll
  for (int mi = 0; mi < 4; ++mi) {
#pragma unroll
    for (int i = 0; i < 4; ++i) {
      int rloc = wm*64 + mi*16 + (lane >> 4)*4 + i;
      int m = m0 + rloc;
      if (m < Me) {
#pragma unroll
        for (int ni = 0; ni < 2; ++ni) {
          int col = n0 + wn*32 + ni*16 + row16;
          ys[(size_t)(rb + m)*DM + col] = acc[mi][ni][i] + bo[e*DM + col];
        }
      }
    }
  }
}

// ---------------- combine: out[t] = w0*ys[r0] + w1*ys[r1] -------------------
__global__ __launch_bounds__(256) void k_combine(
    const float* __restrict__ ys, const int* __restrict__ t2r,
    const int* __restrict__ rbp, const float* __restrict__ wgt,
    float* __restrict__ out)
{
  const int t = blockIdx.x, tid = threadIdx.x;
  const int c0 = t2r[t*2 + 0], c1 = t2r[t*2 + 1];
  const float w0 = wgt[c0], w1 = wgt[c1];
  const int r0 = rbp[c0 >> 11] + (c0 & 2047);
  const int r1 = rbp[c1 >> 11] + (c1 & 2047);
  const float4* p0 = (const float4*)&ys[(size_t)r0*DM];
  const float4* p1 = (const float4*)&ys[(size_t)r1*DM];
  float4* po = (float4*)&out[(size_t)t*DM];
  float4 a = p0[tid], b = p1[tid];
  float4 r;
  r.x = w0*a.x + w1*b.x; r.y = w0*a.y + w1*b.y;
  r.z = w0*a.z + w1*b.z; r.w = w0*a.w + w1*b.w;
  po[tid] = r;
}

extern "C" void kernel_launch(void* const* d_in, const int* in_sizes, int n_in,
                              void* d_out, int out_size, void* d_ws, size_t ws_size,
                              hipStream_t stream)
{
  const float* x  = (const float*)d_in[0];
  const float* W1 = (const float*)d_in[1];
  const float* b1 = (const float*)d_in[2];
  const float* W2 = (const float*)d_in[3];
  const float* b2 = (const float*)d_in[4];
  const float* Wo = (const float*)d_in[5];
  const float* bo = (const float*)d_in[6];
  const float* Wr = (const float*)d_in[7];
  const float* br = (const float*)d_in[8];
  float* out = (float*)d_out;

  char* ws = (char*)d_ws;
  int*   cnt   = (int*)(ws + 0);           // 8 ints
  int*   rb    = (int*)(ws + 64);          // 8 ints
  int*   MTp   = (int*)(ws + 128);         // 1 int
  int*   mtab  = (int*)(ws + 192);         // <=40 ints
  int*   t2r   = (int*)(ws + 4096);        // 16 KB
  int*   idx   = (int*)(ws + 32*1024);     // 64 KB
  float* wgt   = (float*)(ws + 96*1024);   // 64 KB
  float* probs = (float*)(ws + 160*1024);  // 64 KB
  unsigned short* xb  = (unsigned short*)(ws + 256*1024);          // 4 MB
  unsigned short* act = (unsigned short*)(ws + 5ull*1024*1024);    // 16 MB
  float* ysb = (float*)(ws + 21ull*1024*1024);                     // 16 MB
  unsigned short* W1T = (unsigned short*)(ws + 40ull*1024*1024);   // 32 MB [E][H][D]
  unsigned short* W2T = (unsigned short*)(ws + 72ull*1024*1024);   // 32 MB [E][H][D]
  unsigned short* WoT = (unsigned short*)(ws + 104ull*1024*1024);  // 32 MB [E][D][H]

  k_init<<<1, 64, 0, stream>>>(cnt);
  k_wconv<<<512 + 3072, 256, 0, stream>>>(x, Wr, br, cnt, idx, wgt, t2r, probs, xb,
                                          W1, W2, Wo, W1T, W2T, WoT);
  k_finalize<<<1, 256, 0, stream>>>(cnt, rb, probs, out, MTp, mtab);
  k_ffn1b<<<dim3(DH/TN1, MT_MAX), 256, 0, stream>>>(xb, W1T, b1, W2T, b2, cnt, rb, idx, act, MTp, mtab);
  k_ffn2b<<<dim3(DM/TN1, MT_MAX), 256, 0, stream>>>(act, WoT, bo, cnt, rb, ysb, MTp, mtab);
  k_combine<<<T_TOK, 256, 0, stream>>>(ysb, t2r, rb, wgt, out);
}

// Round 6
// 206.424 us; speedup vs baseline: 1.0627x; 1.0627x over previous
//
#include <hip/hip_runtime.h>
#include <hip/hip_bf16.h>

#define T_TOK 2048
#define DM 1024
#define DH 2048
#define NE 8
#define MT_MAX 40   // max live (expert, m-tile) pairs: 4096/128 + 8

using bf16x8 = __attribute__((ext_vector_type(8))) short;
using f32x4  = __attribute__((ext_vector_type(4))) float;

__device__ __forceinline__ unsigned short f2bf(float f) {
  union { float f; unsigned u; } v; v.f = f;
  unsigned r = v.u + 0x7FFFu + ((v.u >> 16) & 1u);
  return (unsigned short)(r >> 16);
}
__device__ __forceinline__ unsigned pk2(float a, float b) {
  return (unsigned)f2bf(a) | ((unsigned)f2bf(b) << 16);
}

// async global->LDS, 16B per lane; dest wave-uniform base (lane*16 implicit)
#define GLOAD16(gsrc, ldst)                                                        \
  __builtin_amdgcn_global_load_lds(                                                \
      (const __attribute__((address_space(1))) unsigned int*)(gsrc),               \
      (__attribute__((address_space(3))) unsigned int*)(ldst), 16, 0, 0)

// ---------------- init: zero per-expert counters ----------------
__global__ void k_init(int* __restrict__ cnt) {
  if (threadIdx.x < NE) cnt[threadIdx.x] = 0;
}

// ==== fused: router (blocks 0..511) + big-granule weight transpose-convert ===
// conv: one 64k x 256n f32 tile per block. Reads: 1KB/row contiguous (full-wave).
// Register 4x4 transpose -> swizzled LDS bf16 [256n][64k] -> one LINEAR 32KB
// global chunk in FFN-staging-ready tiled layout:
//   tile id (per buffer) = e*128 + kt*nnt + nt ; interior unit (n,k16) at
//   tile*16384 + n*64 + k16*8 (shorts).
__global__ __launch_bounds__(256) void k_wconv(
    const float* __restrict__ x, const float* __restrict__ Wr, const float* __restrict__ br,
    int* __restrict__ cnt, int* __restrict__ idx, float* __restrict__ wgt,
    int* __restrict__ t2r, float* __restrict__ probs, unsigned short* __restrict__ xb,
    const float* __restrict__ W1, const float* __restrict__ W2, const float* __restrict__ Wo,
    unsigned short* __restrict__ W1T, unsigned short* __restrict__ W2T,
    unsigned short* __restrict__ WoT)
{
  __shared__ __align__(16) unsigned short tb[256*64];  // 32 KB
  const int tid = threadIdx.x;

  if (blockIdx.x < 512) {
    // ---------------- router path: 4 tokens per block, 1 wave each ----------
    const int wave = tid >> 6, l = tid & 63;
    const int tok = blockIdx.x * 4 + wave;
    float xv[16];
#pragma unroll
    for (int i = 0; i < 16; ++i) xv[i] = x[tok*DM + l + 64*i];
#pragma unroll
    for (int i = 0; i < 16; ++i) xb[tok*DM + l + 64*i] = f2bf(xv[i]);

    float acc[8] = {0.f,0.f,0.f,0.f,0.f,0.f,0.f,0.f};
#pragma unroll
    for (int i = 0; i < 16; ++i) {
      const float4* wp = (const float4*)&Wr[(size_t)(l + 64*i)*NE];
      float4 wa = wp[0], wb = wp[1];
      acc[0] += xv[i]*wa.x; acc[1] += xv[i]*wa.y; acc[2] += xv[i]*wa.z; acc[3] += xv[i]*wa.w;
      acc[4] += xv[i]*wb.x; acc[5] += xv[i]*wb.y; acc[6] += xv[i]*wb.z; acc[7] += xv[i]*wb.w;
    }
#pragma unroll
    for (int e = 0; e < 8; ++e) {
#pragma unroll
      for (int off = 32; off; off >>= 1) acc[e] += __shfl_xor(acc[e], off, 64);
      acc[e] += br[e];
    }
    float mx = acc[0];
#pragma unroll
    for (int e = 1; e < 8; ++e) mx = fmaxf(mx, acc[e]);
    float p[8], s = 0.f;
#pragma unroll
    for (int e = 0; e < 8; ++e) { p[e] = expf(acc[e] - mx); s += p[e]; }
    float inv = 1.f / s;
#pragma unroll
    for (int e = 0; e < 8; ++e) p[e] *= inv;

    // top-2, strict > so lowest index wins ties (matches jax.lax.top_k)
    int e0 = 0; float p0 = p[0];
#pragma unroll
    for (int e = 1; e < 8; ++e) if (p[e] > p0) { p0 = p[e]; e0 = e; }
    int e1 = -1; float p1 = -1.f;
#pragma unroll
    for (int e = 0; e < 8; ++e) { if (e == e0) continue; if (p[e] > p1) { p1 = p[e]; e1 = e; } }

    if (l == 0) {
#pragma unroll
      for (int e = 0; e < 8; ++e) probs[tok*NE + e] = p[e];
      int pos0 = atomicAdd(&cnt[e0], 1);
      idx[e0*T_TOK + pos0] = tok; wgt[e0*T_TOK + pos0] = p0;
      t2r[tok*2 + 0] = e0*T_TOK + pos0;
      int pos1 = atomicAdd(&cnt[e1], 1);
      idx[e1*T_TOK + pos1] = tok; wgt[e1*T_TOK + pos1] = p1;
      t2r[tok*2 + 1] = e1*T_TOK + pos1;
    }
    return;
  }

  // ---------------- conv path: one tile per block -----------------------------
  int tt = blockIdx.x - 512;          // 0..3071
  const float* in; unsigned short* outT; int R, C, nTb;
  if (tt < 1024)      { in = W1; outT = W1T; R = DM; C = DH; nTb = 3; }
  else if (tt < 2048) { in = W2; outT = W2T; R = DM; C = DH; nTb = 3; tt -= 1024; }
  else                { in = Wo; outT = WoT; R = DH; C = DM; nTb = 2; tt -= 2048; }
  const int e  = tt >> 7;
  const int te = tt & 127;                       // = kt*nnt + nt
  const int r0 = (te >> nTb) * 64;               // k origin
  const int c0 = (te & ((1 << nTb) - 1)) * 256;  // n origin

  const int nq = tid & 63;        // n-quad (n = nq*4+j)
  const int kqb = tid >> 6;       // base k-quad

#pragma unroll
  for (int p = 0; p < 4; ++p) {
    const int kq = p*4 + kqb;     // 0..15 : 8B k-slot
    // 4x4 f32 micro-block: rows r0+kq*4+i (full wave covers one row = 1KB)
    float4 v[4];
#pragma unroll
    for (int i = 0; i < 4; ++i)
      v[i] = *(const float4*)&in[((size_t)e*R + r0 + kq*4 + i)*C + c0 + nq*4];
    // register transpose+convert -> swizzled LDS [n][k] (even-const XOR keeps
    // 16B-unit interiors natural: unit (n,k16) lives at k16 ^ ((n>>2)&7))
#pragma unroll
    for (int j = 0; j < 4; ++j) {
      const int n = nq*4 + j;
      uint2 w;
      w.x = pk2(((const float*)&v[0])[j], ((const float*)&v[1])[j]);
      w.y = pk2(((const float*)&v[2])[j], ((const float*)&v[3])[j]);
      const int slot8 = kq ^ ((nq & 7) << 1);
      *(uint2*)((char*)tb + n*128 + slot8*8) = w;
    }
  }
  __syncthreads();

  // drain: swizzled b128 reads -> one fully-linear 32KB chunk
  unsigned short* chunk = outT + (size_t)(blockIdx.x >= 2560 + 512 - 3072 + 3072 ? 0 : 0, (size_t)( ( (e << 7) | te ) ) * 16384);
#pragma unroll
  for (int p2 = 0; p2 < 8; ++p2) {
    const int u = p2*256 + tid;
    const int n = u >> 3, k16 = u & 7;
    const int slot16 = k16 ^ ((n >> 2) & 7);
    uint4 w = *(const uint4*)((const char*)tb + n*128 + slot16*16);
    *(uint4*)&chunk[(size_t)u * 8] = w;
  }
}

// ------ finalize: row_base prefix + lb_loss + compact work table ------------
__global__ __launch_bounds__(256) void k_finalize(
    const int* __restrict__ cnt, int* __restrict__ rb,
    const float* __restrict__ probs, float* __restrict__ out,
    int* __restrict__ MTp, int* __restrict__ mtab)
{
  __shared__ float red[8][256];
  const int tid = threadIdx.x;
  float s[8] = {0.f,0.f,0.f,0.f,0.f,0.f,0.f,0.f};
  for (int t = tid; t < T_TOK; t += 256) {
#pragma unroll
    for (int e = 0; e < 8; ++e) s[e] += probs[t*NE + e];
  }
#pragma unroll
  for (int e = 0; e < 8; ++e) red[e][tid] = s[e];
  __syncthreads();
  for (int w = 128; w > 0; w >>= 1) {
    if (tid < w) {
#pragma unroll
      for (int e = 0; e < 8; ++e) red[e][tid] += red[e][tid + w];
    }
    __syncthreads();
  }
  if (tid == 0) {
    float lb = 0.f;
#pragma unroll
    for (int e = 0; e < 8; ++e) {
      float mean = red[e][0] * (1.f / T_TOK);
      lb += mean * mean;
    }
    out[2097152] = lb * NE;
    int r = 0, mc = 0;
#pragma unroll
    for (int e = 0; e < 8; ++e) {
      rb[e] = r; r += cnt[e];
      int nmt = (cnt[e] + 127) / 128;
      for (int j = 0; j < nmt; ++j) mtab[mc++] = (e << 16) | j;
    }
    *MTp = mc;
  }
}

#define TM1 128
#define TN1 64
#define BKK 64

// ---- FFN1: h,g GEMMs + SwiGLU -> act (bf16). Compact grid, tiled-B layout. --
__global__ __launch_bounds__(256) void k_ffn1b(
    const unsigned short* __restrict__ xb,
    const unsigned short* __restrict__ W1T, const float* __restrict__ b1,
    const unsigned short* __restrict__ W2T, const float* __restrict__ b2,
    const int* __restrict__ cnt, const int* __restrict__ rbp,
    const int* __restrict__ idx, unsigned short* __restrict__ act,
    const int* __restrict__ MTp, const int* __restrict__ mtab)
{
  const int mtg = blockIdx.y;
  if (mtg >= *MTp) return;
  const int code = mtab[mtg];
  const int e = code >> 16, mt = code & 0xffff;
  const int Me = cnt[e];
  const int m0 = mt * TM1;
  const int nt = blockIdx.x;
  const int n0 = nt * TN1;

  __shared__ __align__(16) unsigned short As[TM1*BKK];  // 16 KB
  __shared__ __align__(16) unsigned short Bh[TN1*BKK];  // 8 KB
  __shared__ __align__(16) unsigned short Bg[TN1*BKK];  // 8 KB
  __shared__ int toks[TM1];

  const int tid = threadIdx.x;
  if (tid < TM1) toks[tid] = idx[e*T_TOK + min(m0 + tid, Me - 1)];
  __syncthreads();

  const int lane = tid & 63;
  const int wave = tid >> 6;
  const int wm = wave >> 1, wn = wave & 1;
  const int row16 = lane & 15, kg = lane >> 4;
  const int sl = lane & 7;   // 16B slot within 128B row
  const int lr = lane >> 3;  // row within 8-row wave chunk

  // hoisted stage-source pointers (swizzle folded into the base)
  const unsigned short* asrc[4];
#pragma unroll
  for (int i = 0; i < 4; ++i) {
    int r = (wave*4 + i)*8 + lr;
    asrc[i] = &xb[(size_t)toks[r]*DM + ((sl ^ (r & 7)) * 8)];
  }
  // B in tiled layout: tile (e*16+kt)*8 + n0/256 ; interior (nsub+r)*64 + slot*8
  const unsigned short *bsrc1[2], *bsrc2[2];
  const int nt256 = n0 >> 8, nsub = n0 & 255;
#pragma unroll
  for (int j = 0; j < 2; ++j) {
    int r = (wave*2 + j)*8 + lr;
    size_t gb = ((size_t)e*128 + nt256)*16384 + (size_t)(nsub + r)*64 + ((sl ^ (r & 7)) * 8);
    bsrc1[j] = &W1T[gb]; bsrc2[j] = &W2T[gb];
  }

  f32x4 ah[4][2], ag[4][2];
#pragma unroll
  for (int i = 0; i < 4; ++i)
#pragma unroll
    for (int j = 0; j < 2; ++j) { ah[i][j] = 0.f; ag[i][j] = 0.f; }

  for (int k0 = 0; k0 < DM; k0 += BKK) {
    const size_t bko = (size_t)k0 * 2048;   // 64k -> next k-tile row (8 tiles)
#pragma unroll
    for (int i = 0; i < 4; ++i)
      GLOAD16(asrc[i] + k0, &As[(wave*4 + i)*512]);
#pragma unroll
    for (int j = 0; j < 2; ++j) {
      GLOAD16(bsrc1[j] + bko, &Bh[(wave*2 + j)*512]);
      GLOAD16(bsrc2[j] + bko, &Bg[(wave*2 + j)*512]);
    }
    __syncthreads();
#pragma unroll
    for (int ks = 0; ks < 2; ++ks) {
      const int kslot = ks*4 + kg;
      bf16x8 a[4], vbh[2], vbg[2];
#pragma unroll
      for (int mi = 0; mi < 4; ++mi) {
        int m = wm*64 + mi*16 + row16;
        a[mi] = *(const bf16x8*)&As[m*BKK + ((kslot ^ (m & 7)) * 8)];
      }
#pragma unroll
      for (int ni = 0; ni < 2; ++ni) {
        int n = wn*32 + ni*16 + row16;
        int off = n*BKK + ((kslot ^ (n & 7)) * 8);
        vbh[ni] = *(const bf16x8*)&Bh[off];
        vbg[ni] = *(const bf16x8*)&Bg[off];
      }
#pragma unroll
      for (int mi = 0; mi < 4; ++mi)
#pragma unroll
        for (int ni = 0; ni < 2; ++ni) {
          ah[mi][ni] = __builtin_amdgcn_mfma_f32_16x16x32_bf16(a[mi], vbh[ni], ah[mi][ni], 0, 0, 0);
          ag[mi][ni] = __builtin_amdgcn_mfma_f32_16x16x32_bf16(a[mi], vbg[ni], ag[mi][ni], 0, 0, 0);
        }
    }
    __syncthreads();
  }

  const int rb = rbp[e];
#pragma unroll
  for (int mi = 0; mi < 4; ++mi) {
#pragma unroll
    for (int i = 0; i < 4; ++i) {
      int rloc = wm*64 + mi*16 + (lane >> 4)*4 + i;
      int m = m0 + rloc;
      if (m < Me) {
#pragma unroll
        for (int ni = 0; ni < 2; ++ni) {
          int col = n0 + wn*32 + ni*16 + row16;
          float h = ah[mi][ni][i] + b1[e*DH + col];
          float g = ag[mi][ni][i] + b2[e*DH + col];
          float sg = g / (1.f + __expf(-g));
          act[(size_t)(rb + m)*DH + col] = f2bf(h * sg);
        }
      }
    }
  }
}

// ---- FFN2: act @ WoT -> ys (f32). Compact grid, tiled-B layout. ------------
__global__ __launch_bounds__(256) void k_ffn2b(
    const unsigned short* __restrict__ act,
    const unsigned short* __restrict__ WoT, const float* __restrict__ bo,
    const int* __restrict__ cnt, const int* __restrict__ rbp,
    float* __restrict__ ys,
    const int* __restrict__ MTp, const int* __restrict__ mtab)
{
  const int mtg = blockIdx.y;
  if (mtg >= *MTp) return;
  const int code = mtab[mtg];
  const int e = code >> 16, mt = code & 0xffff;
  const int Me = cnt[e];
  const int m0 = mt * TM1;
  const int nt = blockIdx.x;
  const int n0 = nt * TN1;
  const int rb = rbp[e];

  __shared__ __align__(16) unsigned short As[TM1*BKK];  // 16 KB
  __shared__ __align__(16) unsigned short Bs[TN1*BKK];  // 8 KB

  const int tid = threadIdx.x;
  const int lane = tid & 63;
  const int wave = tid >> 6;
  const int wm = wave >> 1, wn = wave & 1;
  const int row16 = lane & 15, kg = lane >> 4;
  const int sl = lane & 7;
  const int lr = lane >> 3;

  const unsigned short* asrc[4];
#pragma unroll
  for (int i = 0; i < 4; ++i) {
    int r = (wave*4 + i)*8 + lr;
    int grow = rb + min(m0 + r, Me - 1);
    asrc[i] = &act[(size_t)grow*DH + ((sl ^ (r & 7)) * 8)];
  }
  // Wo tiles: (e*32+kt)*4 + n0/256 ; per-64k stride = 4 tiles = k0*1024 shorts
  const unsigned short* bsrc[2];
  const int nt256 = n0 >> 8, nsub = n0 & 255;
#pragma unroll
  for (int j = 0; j < 2; ++j) {
    int r = (wave*2 + j)*8 + lr;
    size_t gb = ((size_t)e*128 + nt256)*16384 + (size_t)(nsub + r)*64 + ((sl ^ (r & 7)) * 8);
    bsrc[j] = &WoT[gb];
  }

  f32x4 acc[4][2];
#pragma unroll
  for (int i = 0; i < 4; ++i)
#pragma unroll
    for (int j = 0; j < 2; ++j) acc[i][j] = 0.f;

  for (int k0 = 0; k0 < DH; k0 += BKK) {
    const size_t bko = (size_t)k0 * 1024;
#pragma unroll
    for (int i = 0; i < 4; ++i)
      GLOAD16(asrc[i] + k0, &As[(wave*4 + i)*512]);
#pragma unroll
    for (int j = 0; j < 2; ++j)
      GLOAD16(bsrc[j] + bko, &Bs[(wave*2 + j)*512]);
    __syncthreads();
#pragma unroll
    for (int ks = 0; ks < 2; ++ks) {
      const int kslot = ks*4 + kg;
      bf16x8 a[4], b[2];
#pragma unroll
      for (int mi = 0; mi < 4; ++mi) {
        int m = wm*64 + mi*16 + row16;
        a[mi] = *(const bf16x8*)&As[m*BKK + ((kslot ^ (m & 7)) * 8)];
      }
#pragma unroll
      for (int ni = 0; ni < 2; ++ni) {
        int n = wn*32 + ni*16 + row16;
        b[ni] = *(const bf16x8*)&Bs[n*BKK + ((kslot ^ (n & 7)) * 8)];
      }
#pragma unroll
      for (int mi = 0; mi < 4; ++mi)
#pragma unroll
        for (int ni = 0; ni < 2; ++ni)
          acc[mi][ni] = __builtin_amdgcn_mfma_f32_16x16x32_bf16(a[mi], b[ni], acc[mi][ni], 0, 0, 0);
    }
    __syncthreads();
  }

#pragma unroll
  for (int mi = 0; mi < 4; ++mi) {
#pragma unroll
    for (int i = 0; i < 4; ++i) {
      int rloc = wm*64 + mi*16 + (lane >> 4)*4 + i;
      int m = m0 + rloc;
      if (m < Me) {
#pragma unroll
        for (int ni = 0; ni < 2; ++ni) {
          int col = n0 + wn*32 + ni*16 + row16;
          ys[(size_t)(rb + m)*DM + col] = acc[mi][ni][i] + bo[e*DM + col];
        }
      }
    }
  }
}

// ---------------- combine: out[t] = w0*ys[r0] + w1*ys[r1] -------------------
__global__ __launch_bounds__(256) void k_combine(
    const float* __restrict__ ys, const int* __restrict__ t2r,
    const int* __restrict__ rbp, const float* __restrict__ wgt,
    float* __restrict__ out)
{
  const int t = blockIdx.x, tid = threadIdx.x;
  const int c0 = t2r[t*2 + 0], c1 = t2r[t*2 + 1];
  const float w0 = wgt[c0], w1 = wgt[c1];
  const int r0 = rbp[c0 >> 11] + (c0 & 2047);
  const int r1 = rbp[c1 >> 11] + (c1 & 2047);
  const float4* p0 = (const float4*)&ys[(size_t)r0*DM];
  const float4* p1 = (const float4*)&ys[(size_t)r1*DM];
  float4* po = (float4*)&out[(size_t)t*DM];
  float4 a = p0[tid], b = p1[tid];
  float4 r;
  r.x = w0*a.x + w1*b.x; r.y = w0*a.y + w1*b.y;
  r.z = w0*a.z + w1*b.z; r.w = w0*a.w + w1*b.w;
  po[tid] = r;
}

extern "C" void kernel_launch(void* const* d_in, const int* in_sizes, int n_in,
                              void* d_out, int out_size, void* d_ws, size_t ws_size,
                              hipStream_t stream)
{
  const float* x  = (const float*)d_in[0];
  const float* W1 = (const float*)d_in[1];
  const float* b1 = (const float*)d_in[2];
  const float* W2 = (const float*)d_in[3];
  const float* b2 = (const float*)d_in[4];
  const float* Wo = (const float*)d_in[5];
  const float* bo = (const float*)d_in[6];
  const float* Wr = (const float*)d_in[7];
  const float* br = (const float*)d_in[8];
  float* out = (float*)d_out;

  char* ws = (char*)d_ws;
  int*   cnt   = (int*)(ws + 0);           // 8 ints
  int*   rb    = (int*)(ws + 64);          // 8 ints
  int*   MTp   = (int*)(ws + 128);         // 1 int
  int*   mtab  = (int*)(ws + 192);         // <=40 ints
  int*   t2r   = (int*)(ws + 4096);        // 16 KB
  int*   idx   = (int*)(ws + 32*1024);     // 64 KB
  float* wgt   = (float*)(ws + 96*1024);   // 64 KB
  float* probs = (float*)(ws + 160*1024);  // 64 KB
  unsigned short* xb  = (unsigned short*)(ws + 256*1024);          // 4 MB
  unsigned short* act = (unsigned short*)(ws + 5ull*1024*1024);    // 16 MB
  float* ysb = (float*)(ws + 21ull*1024*1024);                     // 16 MB
  unsigned short* W1T = (unsigned short*)(ws + 40ull*1024*1024);   // 32 MB tiled
  unsigned short* W2T = (unsigned short*)(ws + 72ull*1024*1024);   // 32 MB tiled
  unsigned short* WoT = (unsigned short*)(ws + 104ull*1024*1024);  // 32 MB tiled

  k_init<<<1, 64, 0, stream>>>(cnt);
  k_wconv<<<512 + 3072, 256, 0, stream>>>(x, Wr, br, cnt, idx, wgt, t2r, probs, xb,
                                          W1, W2, Wo, W1T, W2T, WoT);
  k_finalize<<<1, 256, 0, stream>>>(cnt, rb, probs, out, MTp, mtab);
  k_ffn1b<<<dim3(DH/TN1, MT_MAX), 256, 0, stream>>>(xb, W1T, b1, W2T, b2, cnt, rb, idx, act, MTp, mtab);
  k_ffn2b<<<dim3(DM/TN1, MT_MAX), 256, 0, stream>>>(act, WoT, bo, cnt, rb, ysb, MTp, mtab);
  k_combine<<<T_TOK, 256, 0, stream>>>(ysb, t2r, rb, wgt, out);
}